// Round 3
// baseline (884.443 us; speedup 1.0000x reference)
//
#include <hip/hip_runtime.h>
#include <hip/hip_bf16.h>

typedef __bf16 bf16x8 __attribute__((ext_vector_type(8)));
typedef float f32x4 __attribute__((ext_vector_type(4)));

#define B_ 16
#define N_ 2048
#define C_ 512
#define D_ 64
#define BH 8          // batches per half (ws-footprint reduction)

__device__ __forceinline__ float bf2f(ushort u) {
    union { uint i; float f; } w; w.i = ((uint)u) << 16; return w.f;
}
__device__ __forceinline__ ushort f2bf(float f) {
    union { float f; uint i; } w; w.f = f;
    uint u = w.i;
    u = (u + 0x7fffu + ((u >> 16) & 1u)) >> 16;
    return (ushort)u;
}
__device__ __forceinline__ __bf16 u2b(ushort u) {
    union { ushort s; __bf16 b; } w; w.s = u; return w.b;
}
__device__ __forceinline__ bf16x8 ld8u(const ushort* p) { return *(const bf16x8*)p; }
__device__ __forceinline__ bf16x8 ld8f(const float* p) {
    f32x4 a = *(const f32x4*)p;
    f32x4 b = *(const f32x4*)(p + 4);
    bf16x8 r;
    r[0] = u2b(f2bf(a[0])); r[1] = u2b(f2bf(a[1]));
    r[2] = u2b(f2bf(a[2])); r[3] = u2b(f2bf(a[3]));
    r[4] = u2b(f2bf(b[0])); r[5] = u2b(f2bf(b[1]));
    r[6] = u2b(f2bf(b[2])); r[7] = u2b(f2bf(b[3]));
    return r;
}

// Decide whether float tensors are stored as f32 or bf16.
// Even-indexed ushorts of a bf16 array are sane bf16 values (~N(0,1));
// even-indexed ushorts of an f32 array are low mantissa halves (random exp).
__global__ void probe_kernel(const void* x, int* flag) {
    int lane = threadIdx.x & 63;
    ushort u = ((const ushort*)x)[lane * 2];
    float v = fabsf(bf2f(u));
    bool sane = (v > 9.3e-10f) && (v < 1.1e9f) && (v == v);
    unsigned long long m = __ballot(sane);
    if (threadIdx.x == 0) *flag = (__popcll(m) >= 48) ? 0 : 1;  // 0=bf16, 1=f32
}

// Generic B^T GEMM: out[m, n] = sum_k X[m,k] * W[n,k] + bias[n]
// MODE 0: out row-major [M x NCOLS] (q, k buffers [B*N, 64], always bf16)
// MODE 1: out transposed per batch: out[((m>>11)*C_ + n)*N_ + (m & 2047)]  (v_t, bf16)
template<int NCOLS, int MODE>
__launch_bounds__(256, 2)
__global__ void proj_kernel(const void* __restrict__ X,
                            const void* __restrict__ W,
                            const void* __restrict__ bias,
                            ushort* __restrict__ out,
                            const int* __restrict__ flag,
                            size_t xoff) {
    const int isf32 = *flag;
    const ushort* Xu = (const ushort*)X + xoff;
    const float*  Xf = (const float*)X + xoff;
    const ushort* Wu = (const ushort*)W;
    const float*  Wf = (const float*)W;
    const ushort* Bu = (const ushort*)bias;
    const float*  Bf = (const float*)bias;

    __shared__ ushort lA[64][72];
    __shared__ ushort lB[64][72];
    const int tid  = threadIdx.x;
    const int wave = tid >> 6, lane = tid & 63;
    const int quad = lane >> 4, li = lane & 15;
    const int m0 = blockIdx.x * 64;
    const int n0 = blockIdx.y * 64;

    f32x4 acc[4];
    #pragma unroll
    for (int t = 0; t < 4; ++t) acc[t] = (f32x4){0.f, 0.f, 0.f, 0.f};

    for (int k0 = 0; k0 < C_; k0 += 64) {
        __syncthreads();
        #pragma unroll
        for (int it = 0; it < 2; ++it) {
            int idx = tid + it * 256;
            int row = idx >> 3, seg = idx & 7;
            size_t ea = (size_t)(m0 + row) * C_ + k0 + seg * 8;
            size_t eb = (size_t)(n0 + row) * C_ + k0 + seg * 8;
            if (!isf32) {
                *(bf16x8*)&lA[row][seg * 8] = ld8u(Xu + ea);
                *(bf16x8*)&lB[row][seg * 8] = ld8u(Wu + eb);
            } else {
                *(bf16x8*)&lA[row][seg * 8] = ld8f(Xf + ea);
                *(bf16x8*)&lB[row][seg * 8] = ld8f(Wf + eb);
            }
        }
        __syncthreads();
        #pragma unroll
        for (int ks = 0; ks < 2; ++ks) {
            bf16x8 a = *(const bf16x8*)&lA[wave * 16 + li][ks * 32 + quad * 8];
            #pragma unroll
            for (int t = 0; t < 4; ++t) {
                bf16x8 b = *(const bf16x8*)&lB[t * 16 + li][ks * 32 + quad * 8];
                acc[t] = __builtin_amdgcn_mfma_f32_16x16x32_bf16(a, b, acc[t], 0, 0, 0);
            }
        }
    }

    #pragma unroll
    for (int t = 0; t < 4; ++t) {
        int c = n0 + t * 16 + li;
        float bv = isf32 ? Bf[c] : bf2f(Bu[c]);
        if (MODE == 0) {
            #pragma unroll
            for (int j = 0; j < 4; ++j) {
                int m = m0 + wave * 16 + quad * 4 + j;
                out[(size_t)m * NCOLS + c] = f2bf(acc[t][j] + bv);
            }
        } else {
            int m = m0 + wave * 16 + quad * 4;
            int b = m >> 11, ml = m & (N_ - 1);
            ushort4 pk;
            pk.x = f2bf(acc[t][0] + bv);
            pk.y = f2bf(acc[t][1] + bv);
            pk.z = f2bf(acc[t][2] + bv);
            pk.w = f2bf(acc[t][3] + bv);
            *(ushort4*)(out + ((size_t)(b * C_ + c)) * N_ + ml) = pk;
        }
    }
}

// Flash attention: block = (local batch b, 32-row Q strip). 4 waves.
// qb/kb are pre-offset (bf16 internal); vt is the half-sized [BH, C, N] buffer;
// x/out are BASE pointers (dtype per flag), indexed with global batch b0 + b.
__launch_bounds__(256, 2)
__global__ void attn_kernel(const ushort* __restrict__ qb,
                            const ushort* __restrict__ kb,
                            const ushort* __restrict__ vt,
                            const void* __restrict__ x,
                            const void* __restrict__ gptr,
                            void* __restrict__ out,
                            const int* __restrict__ flag,
                            int b0) {
    const int isf32 = *flag;
    const ushort* xu = (const ushort*)x;
    const float*  xf = (const float*)x;
    ushort* ou = (ushort*)out;
    float*  of = (float*)out;

    __shared__ ushort lQ[32][72];
    __shared__ ushort lK[64][72];
    __shared__ ushort lP[32][72];
    const int tid  = threadIdx.x;
    const int wave = tid >> 6, lane = tid & 63;
    const int quad = lane >> 4, li = lane & 15;
    const int r = wave & 1, c2 = wave >> 1;
    const int b  = blockIdx.y;
    const int q0 = blockIdx.x * 32;

    {   // stage Q strip [32 x 64] once
        int row = tid >> 3, seg = tid & 7;
        *(bf16x8*)&lQ[row][seg * 8] =
            *(const bf16x8*)(qb + ((size_t)(b * N_ + q0 + row)) * D_ + seg * 8);
    }

    float m_i[4], l_i[4];
    #pragma unroll
    for (int j = 0; j < 4; ++j) { m_i[j] = -1e30f; l_i[j] = 0.f; }
    f32x4 acc[16];
    #pragma unroll
    for (int t = 0; t < 16; ++t) acc[t] = (f32x4){0.f, 0.f, 0.f, 0.f};

    for (int kt = 0; kt < N_ / 64; ++kt) {
        const int k0 = kt * 64;
        __syncthreads();   // prev iter's lK/lP reads done (also covers lQ stage)
        #pragma unroll
        for (int it = 0; it < 2; ++it) {
            int idx = tid + it * 256;
            int row = idx >> 3, seg = idx & 7;
            *(bf16x8*)&lK[row][seg * 8] =
                *(const bf16x8*)(kb + ((size_t)(b * N_ + k0 + row)) * D_ + seg * 8);
        }
        __syncthreads();   // lK ready

        // S strip [16 x 64] for this wave's rows
        f32x4 s[4];
        #pragma unroll
        for (int t = 0; t < 4; ++t) s[t] = (f32x4){0.f, 0.f, 0.f, 0.f};
        #pragma unroll
        for (int ks = 0; ks < 2; ++ks) {
            bf16x8 a = *(const bf16x8*)&lQ[r * 16 + li][ks * 32 + quad * 8];
            #pragma unroll
            for (int t = 0; t < 4; ++t) {
                bf16x8 bb = *(const bf16x8*)&lK[t * 16 + li][ks * 32 + quad * 8];
                s[t] = __builtin_amdgcn_mfma_f32_16x16x32_bf16(a, bb, s[t], 0, 0, 0);
            }
        }

        // online softmax; row = 16r + quad*4 + j
        float p[4][4];
        #pragma unroll
        for (int j = 0; j < 4; ++j) {
            float mx = s[0][j];
            #pragma unroll
            for (int t = 1; t < 4; ++t) mx = fmaxf(mx, s[t][j]);
            #pragma unroll
            for (int off = 1; off < 16; off <<= 1)
                mx = fmaxf(mx, __shfl_xor(mx, off, 64));
            float mnew  = fmaxf(m_i[j], mx);
            float alpha = __expf(m_i[j] - mnew);
            float rs = 0.f;
            #pragma unroll
            for (int t = 0; t < 4; ++t) {
                p[t][j] = __expf(s[t][j] - mnew);
                rs += p[t][j];
            }
            #pragma unroll
            for (int off = 1; off < 16; off <<= 1)
                rs += __shfl_xor(rs, off, 64);
            l_i[j] = l_i[j] * alpha + rs;
            m_i[j] = mnew;
            #pragma unroll
            for (int t = 0; t < 16; ++t) acc[t][j] *= alpha;
        }

        // P: C-layout -> A-layout via LDS (c2==0 waves write; values identical across c2)
        if (c2 == 0) {
            #pragma unroll
            for (int t = 0; t < 4; ++t)
                #pragma unroll
                for (int j = 0; j < 4; ++j)
                    lP[r * 16 + quad * 4 + j][t * 16 + li] = f2bf(p[t][j]);
        }
        __syncthreads();   // lP ready

        // O += P * V
        #pragma unroll
        for (int ks = 0; ks < 2; ++ks) {
            bf16x8 a = *(const bf16x8*)&lP[r * 16 + li][ks * 32 + quad * 8];
            const ushort* vbase = vt + (size_t)b * C_ * N_ + k0 + ks * 32 + quad * 8;
            #pragma unroll
            for (int t2 = 0; t2 < 16; ++t2) {
                int c = c2 * 256 + t2 * 16 + li;
                bf16x8 bb = *(const bf16x8*)(vbase + (size_t)c * N_);
                acc[t2] = __builtin_amdgcn_mfma_f32_16x16x32_bf16(a, bb, acc[t2], 0, 0, 0);
            }
        }
    }

    // epilogue: out = gamma * (O / l) + x
    float g = isf32 ? ((const float*)gptr)[0] : bf2f(((const ushort*)gptr)[0]);
    float inv[4];
    #pragma unroll
    for (int j = 0; j < 4; ++j) inv[j] = 1.f / l_i[j];
    #pragma unroll
    for (int t2 = 0; t2 < 16; ++t2) {
        int c = c2 * 256 + t2 * 16 + li;
        #pragma unroll
        for (int j = 0; j < 4; ++j) {
            int n = q0 + r * 16 + quad * 4 + j;
            size_t idx = ((size_t)((b0 + b) * N_ + n)) * C_ + c;
            float xv  = isf32 ? xf[idx] : bf2f(xu[idx]);
            float val = g * (acc[t2][j] * inv[j]) + xv;
            if (isf32) of[idx] = val; else ou[idx] = f2bf(val);
        }
    }
}

extern "C" void kernel_launch(void* const* d_in, const int* in_sizes, int n_in,
                              void* d_out, int out_size, void* d_ws, size_t ws_size,
                              hipStream_t stream) {
    (void)in_sizes; (void)n_in; (void)out_size; (void)ws_size;
    const void* x     = d_in[0];
    const void* Wq    = d_in[1];
    const void* bq    = d_in[2];
    const void* Wk    = d_in[3];
    const void* bk    = d_in[4];
    const void* Wv    = d_in[5];
    const void* bv    = d_in[6];
    const void* gamma = d_in[7];

    // ws layout: flag (256 B) | q 4MB | k 4MB | vt_half 16MB
    int*    flag = (int*)d_ws;
    ushort* q    = (ushort*)((char*)d_ws + 256);
    ushort* kk   = q  + (size_t)B_ * N_ * D_;          // [B, N, 64]
    ushort* vt   = kk + (size_t)B_ * N_ * D_;          // [BH, C, N]

    probe_kernel<<<1, 64, 0, stream>>>(x, flag);

    const int M = B_ * N_;  // 32768
    proj_kernel<D_, 0><<<dim3(M / 64, 1), 256, 0, stream>>>(x, Wq, bq, q,  flag, 0);
    proj_kernel<D_, 0><<<dim3(M / 64, 1), 256, 0, stream>>>(x, Wk, bk, kk, flag, 0);

    for (int h = 0; h < B_ / BH; ++h) {
        const size_t xoff = (size_t)h * BH * N_ * C_;   // element offset
        const size_t qoff = (size_t)h * BH * N_ * D_;
        proj_kernel<C_, 1><<<dim3(BH * N_ / 64, C_ / 64), 256, 0, stream>>>(
            x, Wv, bv, vt, flag, xoff);
        attn_kernel<<<dim3(N_ / 32, BH), 256, 0, stream>>>(
            q + qoff, kk + qoff, vt, x, gamma, d_out, flag, h * BH);
    }
}

// Round 4
// 718.415 us; speedup vs baseline: 1.2311x; 1.2311x over previous
//
#include <hip/hip_runtime.h>
#include <hip/hip_bf16.h>

typedef __bf16 bf16x8 __attribute__((ext_vector_type(8)));
typedef float f32x4 __attribute__((ext_vector_type(4)));

#define B_ 16
#define N_ 2048
#define C_ 512
#define D_ 64
#define BH 8          // batches per half (ws-footprint reduction)

__device__ __forceinline__ float bf2f(ushort u) {
    union { uint i; float f; } w; w.i = ((uint)u) << 16; return w.f;
}
__device__ __forceinline__ ushort f2bf(float f) {
    union { float f; uint i; } w; w.f = f;
    uint u = w.i;
    u = (u + 0x7fffu + ((u >> 16) & 1u)) >> 16;
    return (ushort)u;
}
__device__ __forceinline__ __bf16 u2b(ushort u) {
    union { ushort s; __bf16 b; } w; w.s = u; return w.b;
}
__device__ __forceinline__ bf16x8 ld8u(const ushort* p) { return *(const bf16x8*)p; }
__device__ __forceinline__ bf16x8 ld8f(const float* p) {
    f32x4 a = *(const f32x4*)p;
    f32x4 b = *(const f32x4*)(p + 4);
    bf16x8 r;
    r[0] = u2b(f2bf(a[0])); r[1] = u2b(f2bf(a[1]));
    r[2] = u2b(f2bf(a[2])); r[3] = u2b(f2bf(a[3]));
    r[4] = u2b(f2bf(b[0])); r[5] = u2b(f2bf(b[1]));
    r[6] = u2b(f2bf(b[2])); r[7] = u2b(f2bf(b[3]));
    return r;
}

// Decide whether float tensors are stored as f32 or bf16 (bench: f32).
__global__ void probe_kernel(const void* x, int* flag) {
    int lane = threadIdx.x & 63;
    ushort u = ((const ushort*)x)[lane * 2];
    float v = fabsf(bf2f(u));
    bool sane = (v > 9.3e-10f) && (v < 1.1e9f) && (v == v);
    unsigned long long m = __ballot(sane);
    if (threadIdx.x == 0) *flag = (__popcll(m) >= 48) ? 0 : 1;  // 0=bf16, 1=f32
}

// Generic B^T GEMM: out[m, n] = sum_k X[m,k] * W[n,k] + bias[n]
// MODE 0: out row-major [M x NCOLS] (q, k buffers [B*N, 64], always bf16)
// MODE 1: out transposed per batch: out[((m>>11)*C_ + n)*N_ + (m & 2047)]  (v_t, bf16)
template<int NCOLS, int MODE>
__launch_bounds__(256, 2)
__global__ void proj_kernel(const void* __restrict__ X,
                            const void* __restrict__ W,
                            const void* __restrict__ bias,
                            ushort* __restrict__ out,
                            const int* __restrict__ flag,
                            size_t xoff) {
    const int isf32 = *flag;
    const ushort* Xu = (const ushort*)X + xoff;
    const float*  Xf = (const float*)X + xoff;
    const ushort* Wu = (const ushort*)W;
    const float*  Wf = (const float*)W;
    const ushort* Bu = (const ushort*)bias;
    const float*  Bf = (const float*)bias;

    __shared__ ushort lA[64][72];
    __shared__ ushort lB[64][72];
    const int tid  = threadIdx.x;
    const int wave = tid >> 6, lane = tid & 63;
    const int quad = lane >> 4, li = lane & 15;
    const int m0 = blockIdx.x * 64;
    const int n0 = blockIdx.y * 64;

    f32x4 acc[4];
    #pragma unroll
    for (int t = 0; t < 4; ++t) acc[t] = (f32x4){0.f, 0.f, 0.f, 0.f};

    for (int k0 = 0; k0 < C_; k0 += 64) {
        __syncthreads();
        #pragma unroll
        for (int it = 0; it < 2; ++it) {
            int idx = tid + it * 256;
            int row = idx >> 3, seg = idx & 7;
            size_t ea = (size_t)(m0 + row) * C_ + k0 + seg * 8;
            size_t eb = (size_t)(n0 + row) * C_ + k0 + seg * 8;
            if (!isf32) {
                *(bf16x8*)&lA[row][seg * 8] = ld8u(Xu + ea);
                *(bf16x8*)&lB[row][seg * 8] = ld8u(Wu + eb);
            } else {
                *(bf16x8*)&lA[row][seg * 8] = ld8f(Xf + ea);
                *(bf16x8*)&lB[row][seg * 8] = ld8f(Wf + eb);
            }
        }
        __syncthreads();
        #pragma unroll
        for (int ks = 0; ks < 2; ++ks) {
            bf16x8 a = *(const bf16x8*)&lA[wave * 16 + li][ks * 32 + quad * 8];
            #pragma unroll
            for (int t = 0; t < 4; ++t) {
                bf16x8 b = *(const bf16x8*)&lB[t * 16 + li][ks * 32 + quad * 8];
                acc[t] = __builtin_amdgcn_mfma_f32_16x16x32_bf16(a, b, acc[t], 0, 0, 0);
            }
        }
    }

    #pragma unroll
    for (int t = 0; t < 4; ++t) {
        int c = n0 + t * 16 + li;
        float bv = isf32 ? Bf[c] : bf2f(Bu[c]);
        if (MODE == 0) {
            #pragma unroll
            for (int j = 0; j < 4; ++j) {
                int m = m0 + wave * 16 + quad * 4 + j;
                out[(size_t)m * NCOLS + c] = f2bf(acc[t][j] + bv);
            }
        } else {
            int m = m0 + wave * 16 + quad * 4;
            int b = m >> 11, ml = m & (N_ - 1);
            ushort4 pk;
            pk.x = f2bf(acc[t][0] + bv);
            pk.y = f2bf(acc[t][1] + bv);
            pk.z = f2bf(acc[t][2] + bv);
            pk.w = f2bf(acc[t][3] + bv);
            *(ushort4*)(out + ((size_t)(b * C_ + c)) * N_ + ml) = pk;
        }
    }
}

// Flash attention: block = (local batch b, 32-row Q strip). 4 waves.
// V-fragment loads batched into register arrays and issued EARLY so their
// latency hides behind QK^T + softmax (round-3 counters showed serialized
// load->mfma chains at ~13K cyc/kt with VGPR=92).
__launch_bounds__(256, 2)
__global__ void attn_kernel(const ushort* __restrict__ qb,
                            const ushort* __restrict__ kb,
                            const ushort* __restrict__ vt,
                            const void* __restrict__ x,
                            const void* __restrict__ gptr,
                            void* __restrict__ out,
                            const int* __restrict__ flag,
                            int b0) {
    const int isf32 = *flag;
    const ushort* xu = (const ushort*)x;
    const float*  xf = (const float*)x;
    ushort* ou = (ushort*)out;
    float*  of = (float*)out;

    __shared__ ushort lQ[32][72];
    __shared__ ushort lK[64][72];
    __shared__ ushort lP[32][72];
    const int tid  = threadIdx.x;
    const int wave = tid >> 6, lane = tid & 63;
    const int quad = lane >> 4, li = lane & 15;
    const int r = wave & 1, c2 = wave >> 1;
    const int b  = blockIdx.y;
    const int q0 = blockIdx.x * 32;

    {   // stage Q strip [32 x 64] once
        int row = tid >> 3, seg = tid & 7;
        *(bf16x8*)&lQ[row][seg * 8] =
            *(const bf16x8*)(qb + ((size_t)(b * N_ + q0 + row)) * D_ + seg * 8);
    }

    float m_i[4], l_i[4];
    #pragma unroll
    for (int j = 0; j < 4; ++j) { m_i[j] = -1e30f; l_i[j] = 0.f; }
    f32x4 acc[16];
    #pragma unroll
    for (int t = 0; t < 16; ++t) acc[t] = (f32x4){0.f, 0.f, 0.f, 0.f};

    // per-wave V base: k-offset quad*8, column block c2*256
    const ushort* vb = vt + (size_t)b * C_ * N_ + quad * 8;

    for (int kt = 0; kt < N_ / 64; ++kt) {
        const int k0 = kt * 64;
        __syncthreads();   // prev iter's lK/lP reads done (also covers lQ stage)
        #pragma unroll
        for (int it = 0; it < 2; ++it) {
            int idx = tid + it * 256;
            int row = idx >> 3, seg = idx & 7;
            *(bf16x8*)&lK[row][seg * 8] =
                *(const bf16x8*)(kb + ((size_t)(b * N_ + k0 + row)) * D_ + seg * 8);
        }
        __syncthreads();   // lK ready

        // Issue ks=0 V-fragment loads NOW; latency hides behind S + softmax.
        bf16x8 bb0[16];
        #pragma unroll
        for (int t2 = 0; t2 < 16; ++t2) {
            int c = c2 * 256 + t2 * 16 + li;
            bb0[t2] = *(const bf16x8*)(vb + (size_t)c * N_ + k0);
        }

        // S strip [16 x 64] for this wave's rows
        f32x4 s[4];
        #pragma unroll
        for (int t = 0; t < 4; ++t) s[t] = (f32x4){0.f, 0.f, 0.f, 0.f};
        #pragma unroll
        for (int ks = 0; ks < 2; ++ks) {
            bf16x8 a = *(const bf16x8*)&lQ[r * 16 + li][ks * 32 + quad * 8];
            #pragma unroll
            for (int t = 0; t < 4; ++t) {
                bf16x8 bb = *(const bf16x8*)&lK[t * 16 + li][ks * 32 + quad * 8];
                s[t] = __builtin_amdgcn_mfma_f32_16x16x32_bf16(a, bb, s[t], 0, 0, 0);
            }
        }

        // online softmax; row = 16r + quad*4 + j
        float p[4][4];
        #pragma unroll
        for (int j = 0; j < 4; ++j) {
            float mx = s[0][j];
            #pragma unroll
            for (int t = 1; t < 4; ++t) mx = fmaxf(mx, s[t][j]);
            #pragma unroll
            for (int off = 1; off < 16; off <<= 1)
                mx = fmaxf(mx, __shfl_xor(mx, off, 64));
            float mnew  = fmaxf(m_i[j], mx);
            float alpha = __expf(m_i[j] - mnew);
            float rs = 0.f;
            #pragma unroll
            for (int t = 0; t < 4; ++t) {
                p[t][j] = __expf(s[t][j] - mnew);
                rs += p[t][j];
            }
            #pragma unroll
            for (int off = 1; off < 16; off <<= 1)
                rs += __shfl_xor(rs, off, 64);
            l_i[j] = l_i[j] * alpha + rs;
            m_i[j] = mnew;
            #pragma unroll
            for (int t = 0; t < 16; ++t) acc[t][j] *= alpha;
        }

        // P: C-layout -> A-layout via LDS (c2==0 waves write)
        if (c2 == 0) {
            #pragma unroll
            for (int t = 0; t < 4; ++t)
                #pragma unroll
                for (int j = 0; j < 4; ++j)
                    lP[r * 16 + quad * 4 + j][t * 16 + li] = f2bf(p[t][j]);
        }
        __syncthreads();   // lP ready (also drains bb0 loads — long complete)

        // Issue ks=1 V loads; covered by the ks=0 MFMA block below.
        bf16x8 bb1[16];
        #pragma unroll
        for (int t2 = 0; t2 < 16; ++t2) {
            int c = c2 * 256 + t2 * 16 + li;
            bb1[t2] = *(const bf16x8*)(vb + (size_t)c * N_ + k0 + 32);
        }

        bf16x8 a0 = *(const bf16x8*)&lP[r * 16 + li][quad * 8];
        #pragma unroll
        for (int t2 = 0; t2 < 16; ++t2)
            acc[t2] = __builtin_amdgcn_mfma_f32_16x16x32_bf16(a0, bb0[t2], acc[t2], 0, 0, 0);

        bf16x8 a1 = *(const bf16x8*)&lP[r * 16 + li][32 + quad * 8];
        #pragma unroll
        for (int t2 = 0; t2 < 16; ++t2)
            acc[t2] = __builtin_amdgcn_mfma_f32_16x16x32_bf16(a1, bb1[t2], acc[t2], 0, 0, 0);
    }

    // epilogue: out = gamma * (O / l) + x
    float g = isf32 ? ((const float*)gptr)[0] : bf2f(((const ushort*)gptr)[0]);
    float inv[4];
    #pragma unroll
    for (int j = 0; j < 4; ++j) inv[j] = 1.f / l_i[j];
    #pragma unroll
    for (int t2 = 0; t2 < 16; ++t2) {
        int c = c2 * 256 + t2 * 16 + li;
        #pragma unroll
        for (int j = 0; j < 4; ++j) {
            int n = q0 + r * 16 + quad * 4 + j;
            size_t idx = ((size_t)((b0 + b) * N_ + n)) * C_ + c;
            float xv  = isf32 ? xf[idx] : bf2f(xu[idx]);
            float val = g * (acc[t2][j] * inv[j]) + xv;
            if (isf32) of[idx] = val; else ou[idx] = f2bf(val);
        }
    }
}

extern "C" void kernel_launch(void* const* d_in, const int* in_sizes, int n_in,
                              void* d_out, int out_size, void* d_ws, size_t ws_size,
                              hipStream_t stream) {
    (void)in_sizes; (void)n_in; (void)out_size; (void)ws_size;
    const void* x     = d_in[0];
    const void* Wq    = d_in[1];
    const void* bq    = d_in[2];
    const void* Wk    = d_in[3];
    const void* bk    = d_in[4];
    const void* Wv    = d_in[5];
    const void* bv    = d_in[6];
    const void* gamma = d_in[7];

    // ws layout: flag (256 B) | q 4MB | k 4MB | vt_half 16MB
    int*    flag = (int*)d_ws;
    ushort* q    = (ushort*)((char*)d_ws + 256);
    ushort* kk   = q  + (size_t)B_ * N_ * D_;          // [B, N, 64]
    ushort* vt   = kk + (size_t)B_ * N_ * D_;          // [BH, C, N]

    probe_kernel<<<1, 64, 0, stream>>>(x, flag);

    const int M = B_ * N_;  // 32768
    proj_kernel<D_, 0><<<dim3(M / 64, 1), 256, 0, stream>>>(x, Wq, bq, q,  flag, 0);
    proj_kernel<D_, 0><<<dim3(M / 64, 1), 256, 0, stream>>>(x, Wk, bk, kk, flag, 0);

    for (int h = 0; h < B_ / BH; ++h) {
        const size_t xoff = (size_t)h * BH * N_ * C_;   // element offset
        const size_t qoff = (size_t)h * BH * N_ * D_;
        proj_kernel<C_, 1><<<dim3(BH * N_ / 64, C_ / 64), 256, 0, stream>>>(
            x, Wv, bv, vt, flag, xoff);
        attn_kernel<<<dim3(N_ / 32, BH), 256, 0, stream>>>(
            q + qoff, kk + qoff, vt, x, gamma, d_out, flag, h * BH);
    }
}

// Round 5
// 707.472 us; speedup vs baseline: 1.2501x; 1.0155x over previous
//
#include <hip/hip_runtime.h>
#include <hip/hip_bf16.h>

typedef __bf16 bf16x8 __attribute__((ext_vector_type(8)));
typedef float f32x4 __attribute__((ext_vector_type(4)));

#define B_ 16
#define N_ 2048
#define C_ 512
#define D_ 64
#define BH 8          // batches per attn/projv pass (ws-footprint reduction)
#define NT (N_ / 64)  // 32 k-tiles

__device__ __forceinline__ float bf2f(ushort u) {
    union { uint i; float f; } w; w.i = ((uint)u) << 16; return w.f;
}
__device__ __forceinline__ ushort f2bf(float f) {
    union { float f; uint i; } w; w.f = f;
    uint u = w.i;
    u = (u + 0x7fffu + ((u >> 16) & 1u)) >> 16;
    return (ushort)u;
}
__device__ __forceinline__ __bf16 u2b(ushort u) {
    union { ushort s; __bf16 b; } w; w.s = u; return w.b;
}
__device__ __forceinline__ bf16x8 ld8u(const ushort* p) { return *(const bf16x8*)p; }
__device__ __forceinline__ bf16x8 ld8f(const float* p) {
    f32x4 a = *(const f32x4*)p;
    f32x4 b = *(const f32x4*)(p + 4);
    bf16x8 r;
    r[0] = u2b(f2bf(a[0])); r[1] = u2b(f2bf(a[1]));
    r[2] = u2b(f2bf(a[2])); r[3] = u2b(f2bf(a[3]));
    r[4] = u2b(f2bf(b[0])); r[5] = u2b(f2bf(b[1]));
    r[6] = u2b(f2bf(b[2])); r[7] = u2b(f2bf(b[3]));
    return r;
}

// 16-lane (DPP row) reductions — VALU latency, no LDS pipe.
// quad_perm(1,0,3,2)=0xB1 (xor1), quad_perm(2,3,0,1)=0x4E (xor2),
// row_half_mirror=0x141 (other quad of 8), row_mirror=0x140 (other 8 of 16).
__device__ __forceinline__ float dpp_add16(float x) {
    int v;
    v = __float_as_int(x);
    x += __int_as_float(__builtin_amdgcn_update_dpp(v, v, 0xB1, 0xF, 0xF, true));
    v = __float_as_int(x);
    x += __int_as_float(__builtin_amdgcn_update_dpp(v, v, 0x4E, 0xF, 0xF, true));
    v = __float_as_int(x);
    x += __int_as_float(__builtin_amdgcn_update_dpp(v, v, 0x141, 0xF, 0xF, true));
    v = __float_as_int(x);
    x += __int_as_float(__builtin_amdgcn_update_dpp(v, v, 0x140, 0xF, 0xF, true));
    return x;
}
__device__ __forceinline__ float dpp_max16(float x) {
    int v;
    v = __float_as_int(x);
    x = fmaxf(x, __int_as_float(__builtin_amdgcn_update_dpp(v, v, 0xB1, 0xF, 0xF, true)));
    v = __float_as_int(x);
    x = fmaxf(x, __int_as_float(__builtin_amdgcn_update_dpp(v, v, 0x4E, 0xF, 0xF, true)));
    v = __float_as_int(x);
    x = fmaxf(x, __int_as_float(__builtin_amdgcn_update_dpp(v, v, 0x141, 0xF, 0xF, true)));
    v = __float_as_int(x);
    x = fmaxf(x, __int_as_float(__builtin_amdgcn_update_dpp(v, v, 0x140, 0xF, 0xF, true)));
    return x;
}

// Decide whether float tensors are stored as f32 or bf16 (bench: f32).
__global__ void probe_kernel(const void* x, int* flag) {
    int lane = threadIdx.x & 63;
    ushort u = ((const ushort*)x)[lane * 2];
    float v = fabsf(bf2f(u));
    bool sane = (v > 9.3e-10f) && (v < 1.1e9f) && (v == v);
    unsigned long long m = __ballot(sane);
    if (threadIdx.x == 0) *flag = (__popcll(m) >= 48) ? 0 : 1;  // 0=bf16, 1=f32
}

// Generic B^T GEMM: out[m, n] = sum_k X[m,k] * W[n,k] + bias[n]
// MODE 0: out row-major [M x NCOLS]; MODE 1: out transposed per batch (v_t).
template<int NCOLS, int MODE>
__launch_bounds__(256, 2)
__global__ void proj_kernel(const void* __restrict__ X,
                            const void* __restrict__ W,
                            const void* __restrict__ bias,
                            ushort* __restrict__ out,
                            const int* __restrict__ flag,
                            size_t xoff) {
    const int isf32 = *flag;
    const ushort* Xu = (const ushort*)X + xoff;
    const float*  Xf = (const float*)X + xoff;
    const ushort* Wu = (const ushort*)W;
    const float*  Wf = (const float*)W;
    const ushort* Bu = (const ushort*)bias;
    const float*  Bf = (const float*)bias;

    __shared__ ushort lA[64][72];
    __shared__ ushort lB[64][72];
    const int tid  = threadIdx.x;
    const int wave = tid >> 6, lane = tid & 63;
    const int quad = lane >> 4, li = lane & 15;
    const int m0 = blockIdx.x * 64;
    const int n0 = blockIdx.y * 64;

    f32x4 acc[4];
    #pragma unroll
    for (int t = 0; t < 4; ++t) acc[t] = (f32x4){0.f, 0.f, 0.f, 0.f};

    for (int k0 = 0; k0 < C_; k0 += 64) {
        __syncthreads();
        #pragma unroll
        for (int it = 0; it < 2; ++it) {
            int idx = tid + it * 256;
            int row = idx >> 3, seg = idx & 7;
            size_t ea = (size_t)(m0 + row) * C_ + k0 + seg * 8;
            size_t eb = (size_t)(n0 + row) * C_ + k0 + seg * 8;
            if (!isf32) {
                *(bf16x8*)&lA[row][seg * 8] = ld8u(Xu + ea);
                *(bf16x8*)&lB[row][seg * 8] = ld8u(Wu + eb);
            } else {
                *(bf16x8*)&lA[row][seg * 8] = ld8f(Xf + ea);
                *(bf16x8*)&lB[row][seg * 8] = ld8f(Wf + eb);
            }
        }
        __syncthreads();
        #pragma unroll
        for (int ks = 0; ks < 2; ++ks) {
            bf16x8 a = *(const bf16x8*)&lA[wave * 16 + li][ks * 32 + quad * 8];
            #pragma unroll
            for (int t = 0; t < 4; ++t) {
                bf16x8 b = *(const bf16x8*)&lB[t * 16 + li][ks * 32 + quad * 8];
                acc[t] = __builtin_amdgcn_mfma_f32_16x16x32_bf16(a, b, acc[t], 0, 0, 0);
            }
        }
    }

    #pragma unroll
    for (int t = 0; t < 4; ++t) {
        int c = n0 + t * 16 + li;
        float bv = isf32 ? Bf[c] : bf2f(Bu[c]);
        if (MODE == 0) {
            #pragma unroll
            for (int j = 0; j < 4; ++j) {
                int m = m0 + wave * 16 + quad * 4 + j;
                out[(size_t)m * NCOLS + c] = f2bf(acc[t][j] + bv);
            }
        } else {
            int m = m0 + wave * 16 + quad * 4;
            int b = m >> 11, ml = m & (N_ - 1);
            ushort4 pk;
            pk.x = f2bf(acc[t][0] + bv);
            pk.y = f2bf(acc[t][1] + bv);
            pk.z = f2bf(acc[t][2] + bv);
            pk.w = f2bf(acc[t][3] + bv);
            *(ushort4*)(out + ((size_t)(b * C_ + c)) * N_ + ml) = pk;
        }
    }
}

// Flash attention, round-5 structure:
//  - grid (N/32, BH*2): blockIdx.y = (batch<<1)|colhalf; each block owns 256 C-cols
//  - 2 barriers/iter: lK double-buffered, next-K prefetched into registers
//  - all V-fragment loads issued right after the lK barrier (drain at lP barrier
//    is covered by S + DPP softmax)
//  - 16-lane reductions via DPP (VALU) instead of ds_swizzle chains
__launch_bounds__(256, 3)
__global__ void attn_kernel(const ushort* __restrict__ qb,
                            const ushort* __restrict__ kb,
                            const ushort* __restrict__ vt,
                            const void* __restrict__ x,
                            const void* __restrict__ gptr,
                            void* __restrict__ out,
                            const int* __restrict__ flag,
                            int b0) {
    const int isf32 = *flag;
    const ushort* xu = (const ushort*)x;
    const float*  xf = (const float*)x;
    ushort* ou = (ushort*)out;
    float*  of = (float*)out;

    __shared__ ushort lQ[32][72];
    __shared__ ushort lK[2][64][72];
    __shared__ ushort lP[32][72];
    const int tid  = threadIdx.x;
    const int wave = tid >> 6, lane = tid & 63;
    const int quad = lane >> 4, li = lane & 15;
    const int r = wave & 1, c2 = wave >> 1;
    const int b  = blockIdx.y >> 1;
    const int ch = blockIdx.y & 1;           // column half: 256 cols
    const int q0 = blockIdx.x * 32;
    const int cbase = ch * 256 + c2 * 128;   // this wave's 128-col block

    const int srow = tid >> 3, sseg = tid & 7;   // staging coords (512 thr / 64 rows)

    {   // stage Q strip [32 x 64] once (rows 0..31 by tid>>3 over two halves)
        *(bf16x8*)&lQ[srow][sseg * 8] =
            *(const bf16x8*)(qb + ((size_t)(b * N_ + q0 + srow)) * D_ + sseg * 8);
    }

    // preload K-tile 0 into registers
    bf16x8 kr0, kr1;
    {
        const ushort* kbase = kb + (size_t)b * N_ * D_;
        kr0 = *(const bf16x8*)(kbase + (size_t)(srow)      * D_ + sseg * 8);
        kr1 = *(const bf16x8*)(kbase + (size_t)(srow + 32) * D_ + sseg * 8);
    }

    float m_i[4], l_i[4];
    #pragma unroll
    for (int j = 0; j < 4; ++j) { m_i[j] = -1e30f; l_i[j] = 0.f; }
    f32x4 acc[8];
    #pragma unroll
    for (int t = 0; t < 8; ++t) acc[t] = (f32x4){0.f, 0.f, 0.f, 0.f};

    const ushort* vb = vt + (size_t)b * C_ * N_ + quad * 8;

    for (int kt = 0; kt < NT; ++kt) {
        const int k0 = kt * 64;
        const int buf = kt & 1;

        // write current K tile from registers (prev readers of this buf
        // finished >= 2 barriers ago)
        *(bf16x8*)&lK[buf][srow][sseg * 8]      = kr0;
        *(bf16x8*)&lK[buf][srow + 32][sseg * 8] = kr1;
        __syncthreads();   // barrier 1: lK[buf] ready; prev-iter lP reads done

        // issue next K-tile + ALL V-fragment loads now; the only drain point
        // (barrier 2) comes after S + softmax
        {
            int ktn = (kt + 1 < NT) ? kt + 1 : kt;
            const ushort* kbase = kb + (size_t)b * N_ * D_ + (size_t)ktn * 64 * D_;
            kr0 = *(const bf16x8*)(kbase + (size_t)(srow)      * D_ + sseg * 8);
            kr1 = *(const bf16x8*)(kbase + (size_t)(srow + 32) * D_ + sseg * 8);
        }
        bf16x8 bb0[8], bb1[8];
        #pragma unroll
        for (int t2 = 0; t2 < 8; ++t2) {
            int c = cbase + t2 * 16 + li;
            bb0[t2] = *(const bf16x8*)(vb + (size_t)c * N_ + k0);
            bb1[t2] = *(const bf16x8*)(vb + (size_t)c * N_ + k0 + 32);
        }

        // S strip [16 x 64] for this wave's rows
        f32x4 s[4];
        #pragma unroll
        for (int t = 0; t < 4; ++t) s[t] = (f32x4){0.f, 0.f, 0.f, 0.f};
        #pragma unroll
        for (int ks = 0; ks < 2; ++ks) {
            bf16x8 a = *(const bf16x8*)&lQ[r * 16 + li][ks * 32 + quad * 8];
            #pragma unroll
            for (int t = 0; t < 4; ++t) {
                bf16x8 bb = *(const bf16x8*)&lK[buf][t * 16 + li][ks * 32 + quad * 8];
                s[t] = __builtin_amdgcn_mfma_f32_16x16x32_bf16(a, bb, s[t], 0, 0, 0);
            }
        }

        // online softmax (DPP 16-lane reductions); row = 16r + quad*4 + j
        float p[4][4];
        #pragma unroll
        for (int j = 0; j < 4; ++j) {
            float mx = fmaxf(fmaxf(s[0][j], s[1][j]), fmaxf(s[2][j], s[3][j]));
            mx = dpp_max16(mx);
            float mnew  = fmaxf(m_i[j], mx);
            float alpha = __expf(m_i[j] - mnew);
            float rs = 0.f;
            #pragma unroll
            for (int t = 0; t < 4; ++t) {
                p[t][j] = __expf(s[t][j] - mnew);
                rs += p[t][j];
            }
            rs = dpp_add16(rs);
            l_i[j] = l_i[j] * alpha + rs;
            m_i[j] = mnew;
            #pragma unroll
            for (int t = 0; t < 8; ++t) acc[t][j] *= alpha;
        }

        // P: C-layout -> A-layout via LDS (one wave per r writes)
        if (c2 == 0) {
            #pragma unroll
            for (int t = 0; t < 4; ++t)
                #pragma unroll
                for (int j = 0; j < 4; ++j)
                    lP[r * 16 + quad * 4 + j][t * 16 + li] = f2bf(p[t][j]);
        }
        __syncthreads();   // barrier 2: lP ready (drains V/K loads — covered)

        // O += P * V (V fragments already in registers)
        bf16x8 a0 = *(const bf16x8*)&lP[r * 16 + li][quad * 8];
        #pragma unroll
        for (int t2 = 0; t2 < 8; ++t2)
            acc[t2] = __builtin_amdgcn_mfma_f32_16x16x32_bf16(a0, bb0[t2], acc[t2], 0, 0, 0);
        bf16x8 a1 = *(const bf16x8*)&lP[r * 16 + li][32 + quad * 8];
        #pragma unroll
        for (int t2 = 0; t2 < 8; ++t2)
            acc[t2] = __builtin_amdgcn_mfma_f32_16x16x32_bf16(a1, bb1[t2], acc[t2], 0, 0, 0);
    }

    // epilogue: out = gamma * (O / l) + x
    float g = isf32 ? ((const float*)gptr)[0] : bf2f(((const ushort*)gptr)[0]);
    float inv[4];
    #pragma unroll
    for (int j = 0; j < 4; ++j) inv[j] = 1.f / l_i[j];
    #pragma unroll
    for (int t2 = 0; t2 < 8; ++t2) {
        int c = cbase + t2 * 16 + li;
        #pragma unroll
        for (int j = 0; j < 4; ++j) {
            int n = q0 + r * 16 + quad * 4 + j;
            size_t idx = ((size_t)((b0 + b) * N_ + n)) * C_ + c;
            float xv  = isf32 ? xf[idx] : bf2f(xu[idx]);
            float val = g * (acc[t2][j] * inv[j]) + xv;
            if (isf32) of[idx] = val; else ou[idx] = f2bf(val);
        }
    }
}

extern "C" void kernel_launch(void* const* d_in, const int* in_sizes, int n_in,
                              void* d_out, int out_size, void* d_ws, size_t ws_size,
                              hipStream_t stream) {
    (void)in_sizes; (void)n_in; (void)out_size; (void)ws_size;
    const void* x     = d_in[0];
    const void* Wq    = d_in[1];
    const void* bq    = d_in[2];
    const void* Wk    = d_in[3];
    const void* bk    = d_in[4];
    const void* Wv    = d_in[5];
    const void* bv    = d_in[6];
    const void* gamma = d_in[7];

    // ws layout: flag (256 B) | q 4MB | k 4MB | vt_half 16MB
    int*    flag = (int*)d_ws;
    ushort* q    = (ushort*)((char*)d_ws + 256);
    ushort* kk   = q  + (size_t)B_ * N_ * D_;          // [B, N, 64]
    ushort* vt   = kk + (size_t)B_ * N_ * D_;          // [BH, C, N]

    probe_kernel<<<1, 64, 0, stream>>>(x, flag);

    const int M = B_ * N_;  // 32768
    proj_kernel<D_, 0><<<dim3(M / 64, 1), 256, 0, stream>>>(x, Wq, bq, q,  flag, 0);
    proj_kernel<D_, 0><<<dim3(M / 64, 1), 256, 0, stream>>>(x, Wk, bk, kk, flag, 0);

    for (int h = 0; h < B_ / BH; ++h) {
        const size_t xoff = (size_t)h * BH * N_ * C_;   // element offset
        const size_t qoff = (size_t)h * BH * N_ * D_;
        proj_kernel<C_, 1><<<dim3(BH * N_ / 64, C_ / 64), 256, 0, stream>>>(
            x, Wv, bv, vt, flag, xoff);
        attn_kernel<<<dim3(N_ / 32, BH * 2), 256, 0, stream>>>(
            q + qoff, kk + qoff, vt, x, gamma, d_out, flag, h * BH);
    }
}

// Round 6
// 413.890 us; speedup vs baseline: 2.1369x; 1.7093x over previous
//
#include <hip/hip_runtime.h>
#include <hip/hip_bf16.h>

typedef __bf16 bf16x8 __attribute__((ext_vector_type(8)));
typedef float f32x4 __attribute__((ext_vector_type(4)));

#define B_ 16
#define N_ 2048
#define C_ 512
#define D_ 64

__device__ __forceinline__ float bf2f(ushort u) {
    union { uint i; float f; } w; w.i = ((uint)u) << 16; return w.f;
}
__device__ __forceinline__ ushort f2bf(float f) {
    union { float f; uint i; } w; w.f = f;
    uint u = w.i;
    u = (u + 0x7fffu + ((u >> 16) & 1u)) >> 16;
    return (ushort)u;
}
__device__ __forceinline__ __bf16 u2b(ushort u) {
    union { ushort s; __bf16 b; } w; w.s = u; return w.b;
}
__device__ __forceinline__ bf16x8 ld8u(const ushort* p) { return *(const bf16x8*)p; }
__device__ __forceinline__ bf16x8 ld8f(const float* p) {
    f32x4 a = *(const f32x4*)p;
    f32x4 b = *(const f32x4*)(p + 4);
    bf16x8 r;
    r[0] = u2b(f2bf(a[0])); r[1] = u2b(f2bf(a[1]));
    r[2] = u2b(f2bf(a[2])); r[3] = u2b(f2bf(a[3]));
    r[4] = u2b(f2bf(b[0])); r[5] = u2b(f2bf(b[1]));
    r[6] = u2b(f2bf(b[2])); r[7] = u2b(f2bf(b[3]));
    return r;
}

// async global->LDS, 16 B per lane; LDS dest = wave-uniform base + lane*16
__device__ __forceinline__ void gload16(const ushort* g, ushort* l) {
    __builtin_amdgcn_global_load_lds(
        (const __attribute__((address_space(1))) void*)g,
        (__attribute__((address_space(3))) void*)l, 16, 0, 0);
}

// Decide whether float tensors are stored as f32 or bf16 (bench: f32).
__global__ void probe_kernel(const void* x, int* flag) {
    int lane = threadIdx.x & 63;
    ushort u = ((const ushort*)x)[lane * 2];
    float v = fabsf(bf2f(u));
    bool sane = (v > 9.3e-10f) && (v < 1.1e9f) && (v == v);
    unsigned long long m = __ballot(sane);
    if (threadIdx.x == 0) *flag = (__popcll(m) >= 48) ? 0 : 1;  // 0=bf16, 1=f32
}

// Generic B^T GEMM: out[m, n] = sum_k X[m,k] * W[n,k] + bias[n]
// MODE 0: out row-major [M x NCOLS]; MODE 1: out transposed per batch (v_t).
template<int NCOLS, int MODE>
__launch_bounds__(256, 2)
__global__ void proj_kernel(const void* __restrict__ X,
                            const void* __restrict__ W,
                            const void* __restrict__ bias,
                            ushort* __restrict__ out,
                            const int* __restrict__ flag,
                            size_t xoff) {
    const int isf32 = *flag;
    const ushort* Xu = (const ushort*)X + xoff;
    const float*  Xf = (const float*)X + xoff;
    const ushort* Wu = (const ushort*)W;
    const float*  Wf = (const float*)W;
    const ushort* Bu = (const ushort*)bias;
    const float*  Bf = (const float*)bias;

    __shared__ ushort lA[64][72];
    __shared__ ushort lB[64][72];
    const int tid  = threadIdx.x;
    const int wave = tid >> 6, lane = tid & 63;
    const int quad = lane >> 4, li = lane & 15;
    const int m0 = blockIdx.x * 64;
    const int n0 = blockIdx.y * 64;

    f32x4 acc[4];
    #pragma unroll
    for (int t = 0; t < 4; ++t) acc[t] = (f32x4){0.f, 0.f, 0.f, 0.f};

    for (int k0 = 0; k0 < C_; k0 += 64) {
        __syncthreads();
        #pragma unroll
        for (int it = 0; it < 2; ++it) {
            int idx = tid + it * 256;
            int row = idx >> 3, seg = idx & 7;
            size_t ea = (size_t)(m0 + row) * C_ + k0 + seg * 8;
            size_t eb = (size_t)(n0 + row) * C_ + k0 + seg * 8;
            if (!isf32) {
                *(bf16x8*)&lA[row][seg * 8] = ld8u(Xu + ea);
                *(bf16x8*)&lB[row][seg * 8] = ld8u(Wu + eb);
            } else {
                *(bf16x8*)&lA[row][seg * 8] = ld8f(Xf + ea);
                *(bf16x8*)&lB[row][seg * 8] = ld8f(Wf + eb);
            }
        }
        __syncthreads();
        #pragma unroll
        for (int ks = 0; ks < 2; ++ks) {
            bf16x8 a = *(const bf16x8*)&lA[wave * 16 + li][ks * 32 + quad * 8];
            #pragma unroll
            for (int t = 0; t < 4; ++t) {
                bf16x8 b = *(const bf16x8*)&lB[t * 16 + li][ks * 32 + quad * 8];
                acc[t] = __builtin_amdgcn_mfma_f32_16x16x32_bf16(a, b, acc[t], 0, 0, 0);
            }
        }
    }

    #pragma unroll
    for (int t = 0; t < 4; ++t) {
        int c = n0 + t * 16 + li;
        float bv = isf32 ? Bf[c] : bf2f(Bu[c]);
        if (MODE == 0) {
            #pragma unroll
            for (int j = 0; j < 4; ++j) {
                int m = m0 + wave * 16 + quad * 4 + j;
                out[(size_t)m * NCOLS + c] = f2bf(acc[t][j] + bv);
            }
        } else {
            int m = m0 + wave * 16 + quad * 4;
            int b = m >> 11, ml = m & (N_ - 1);
            ushort4 pk;
            pk.x = f2bf(acc[t][0] + bv);
            pk.y = f2bf(acc[t][1] + bv);
            pk.z = f2bf(acc[t][2] + bv);
            pk.w = f2bf(acc[t][3] + bv);
            *(ushort4*)(out + ((size_t)(b * C_ + c)) * N_ + ml) = pk;
        }
    }
}

// m97-style 128x128 GEMM, B^T convention: D[n, c] = sum_k A[n,k] * B[c,k].
// global_load_lds (16B/lane) staging into XOR-swizzled LDS (granule g of row r
// stored at r*8 + (g ^ (r&7)) -> conflict-free ds_read_b128 fragments).
// EPI 0: D -> bf16 Sout[bz*N*N + n*N + c]   (S = Q K^T)
// EPI 1: out = gamma * D / l[n] + x         (O = P~ V, fused epilogue)
template<int KTOT, int SA, int SB, int EPI>
__launch_bounds__(256, 2)
__global__ void gemm128(const ushort* __restrict__ Abase,
                        const ushort* __restrict__ Bbase,
                        ushort* __restrict__ Sout,
                        const float* __restrict__ lrow,
                        const void* __restrict__ x,
                        const void* __restrict__ gptr,
                        void* __restrict__ out,
                        const int* __restrict__ flag,
                        int b0, size_t aBS, size_t bBS) {
    __shared__ ushort lA[128 * 64];
    __shared__ ushort lB[128 * 64];
    const int tid  = threadIdx.x;
    const int wave = tid >> 6, lane = tid & 63;
    const int quad = lane >> 4, li = lane & 15;
    const int wr = (wave & 1) * 64;    // wave's row block within the 128-tile
    const int wc = (wave >> 1) * 64;   // wave's col block
    const int bz = blockIdx.z;
    const int m0 = blockIdx.x * 128;   // n rows
    const int c0 = blockIdx.y * 128;   // cols (B rows)
    const ushort* A  = Abase + (size_t)bz * aBS;
    const ushort* Bp = Bbase + (size_t)bz * bBS;

    // staging lane constants: lane covers row (+lane>>3), XOR'd k-segment
    const int lrow8 = lane >> 3;
    const int lseg  = (lane & 7) ^ (lrow8 & 7);

    f32x4 acc[4][4];
    #pragma unroll
    for (int i = 0; i < 4; ++i)
        #pragma unroll
        for (int j = 0; j < 4; ++j) acc[i][j] = (f32x4){0.f, 0.f, 0.f, 0.f};

    for (int k0 = 0; k0 < KTOT; k0 += 64) {
        __syncthreads();   // prev iter's ds_reads done before overwrite
        #pragma unroll
        for (int i = 0; i < 4; ++i) {
            int rbase = wave * 32 + i * 8;
            int rA = m0 + rbase + lrow8;
            int rB = c0 + rbase + lrow8;
            gload16(A  + (size_t)rA * SA + k0 + lseg * 8, &lA[rbase * 64]);
            gload16(Bp + (size_t)rB * SB + k0 + lseg * 8, &lB[rbase * 64]);
        }
        __syncthreads();   // drains vmcnt: LDS tiles ready

        #pragma unroll
        for (int ks = 0; ks < 2; ++ks) {
            bf16x8 af[4], bfr[4];
            #pragma unroll
            for (int i = 0; i < 4; ++i) {
                int row = wr + i * 16 + li;
                af[i] = *(const bf16x8*)&lA[row * 64 + (((ks * 4 + quad) ^ (li & 7)) * 8)];
            }
            #pragma unroll
            for (int j = 0; j < 4; ++j) {
                int row = wc + j * 16 + li;
                bfr[j] = *(const bf16x8*)&lB[row * 64 + (((ks * 4 + quad) ^ (li & 7)) * 8)];
            }
            #pragma unroll
            for (int i = 0; i < 4; ++i)
                #pragma unroll
                for (int j = 0; j < 4; ++j)
                    acc[i][j] = __builtin_amdgcn_mfma_f32_16x16x32_bf16(
                        af[i], bfr[j], acc[i][j], 0, 0, 0);
        }
    }

    if (EPI == 0) {
        ushort* Sb = Sout + (size_t)bz * N_ * N_;
        #pragma unroll
        for (int i = 0; i < 4; ++i)
            #pragma unroll
            for (int j = 0; j < 4; ++j) {
                int n = m0 + wr + i * 16 + quad * 4 + j;
                #pragma unroll
                for (int j2 = 0; j2 < 4; ++j2) {
                    int m = c0 + wc + j2 * 16 + li;
                    Sb[(size_t)n * N_ + m] = f2bf(acc[i][j2][j]);
                }
            }
    } else {
        const int isf32 = *flag;
        const ushort* xu = (const ushort*)x;
        const float*  xf = (const float*)x;
        ushort* ou = (ushort*)out;
        float*  of = (float*)out;
        float g = isf32 ? ((const float*)gptr)[0] : bf2f(((const ushort*)gptr)[0]);
        #pragma unroll
        for (int i = 0; i < 4; ++i) {
            #pragma unroll
            for (int j = 0; j < 4; ++j) {
                int n = m0 + wr + i * 16 + quad * 4 + j;
                float inv = 1.f / lrow[(size_t)bz * N_ + n];
                size_t rowb = ((size_t)((b0 + bz) * N_ + n)) * C_;
                #pragma unroll
                for (int j2 = 0; j2 < 4; ++j2) {
                    int c = c0 + wc + j2 * 16 + li;
                    size_t idx = rowb + c;
                    float xv  = isf32 ? xf[idx] : bf2f(xu[idx]);
                    float val = g * (acc[i][j2][j] * inv) + xv;
                    if (isf32) of[idx] = val; else ou[idx] = f2bf(val);
                }
            }
        }
    }
}

// Row softmax over S (bf16, in-place -> P~ = exp(s - max)), rowsum -> lrow.
// One wave per row, 4 rows per block.
__launch_bounds__(256, 4)
__global__ void softmax_kernel(ushort* __restrict__ S, float* __restrict__ lrow) {
    const int wave = threadIdx.x >> 6, lane = threadIdx.x & 63;
    const size_t row = (size_t)blockIdx.x * 4 + wave;
    ushort* p = S + row * N_;

    bf16x8 v[4];
    #pragma unroll
    for (int i = 0; i < 4; ++i)
        v[i] = *(const bf16x8*)(p + ((size_t)(i * 64 + lane)) * 8);

    float mx = -1e30f;
    #pragma unroll
    for (int i = 0; i < 4; ++i)
        #pragma unroll
        for (int j = 0; j < 8; ++j) mx = fmaxf(mx, (float)v[i][j]);
    #pragma unroll
    for (int off = 1; off < 64; off <<= 1)
        mx = fmaxf(mx, __shfl_xor(mx, off, 64));

    float sum = 0.f;
    #pragma unroll
    for (int i = 0; i < 4; ++i) {
        bf16x8 w;
        #pragma unroll
        for (int j = 0; j < 8; ++j) {
            float e = __expf((float)v[i][j] - mx);
            sum += e;
            w[j] = u2b(f2bf(e));
        }
        *(bf16x8*)(p + ((size_t)(i * 64 + lane)) * 8) = w;
    }
    #pragma unroll
    for (int off = 1; off < 64; off <<= 1)
        sum += __shfl_xor(sum, off, 64);
    if (lane == 0) lrow[row] = sum;
}

extern "C" void kernel_launch(void* const* d_in, const int* in_sizes, int n_in,
                              void* d_out, int out_size, void* d_ws, size_t ws_size,
                              hipStream_t stream) {
    (void)in_sizes; (void)n_in; (void)out_size;
    const void* x     = d_in[0];
    const void* Wq    = d_in[1];
    const void* bq    = d_in[2];
    const void* Wk    = d_in[3];
    const void* bk    = d_in[4];
    const void* Wv    = d_in[5];
    const void* bv    = d_in[6];
    const void* gamma = d_in[7];

    // choose batch-group size from ws_size (constant across calls -> graph-safe)
    // need(bh) = 256 + q(4M) + k(4M) + bh*( vt 2M + S 8M + l 8K )
    auto need = [](int bh) -> size_t {
        return 256 + 2 * (size_t)B_ * N_ * D_ * 2 +
               (size_t)bh * ((size_t)C_ * N_ * 2 + (size_t)N_ * N_ * 2 + (size_t)N_ * 4);
    };
    int BHg = 1;
    if      (need(8) <= ws_size) BHg = 8;
    else if (need(4) <= ws_size) BHg = 4;
    else if (need(2) <= ws_size) BHg = 2;

    int*    flag = (int*)d_ws;
    ushort* q    = (ushort*)((char*)d_ws + 256);
    ushort* kk   = q  + (size_t)B_ * N_ * D_;           // [B, N, 64] bf16
    ushort* vt   = kk + (size_t)B_ * N_ * D_;           // [BHg, C, N] bf16
    ushort* S    = vt + (size_t)BHg * C_ * N_;          // [BHg, N, N] bf16
    float*  lrow = (float*)(S + (size_t)BHg * N_ * N_); // [BHg, N]

    probe_kernel<<<1, 64, 0, stream>>>(x, flag);

    const int M = B_ * N_;  // 32768
    proj_kernel<D_, 0><<<dim3(M / 64, 1), 256, 0, stream>>>(x, Wq, bq, q,  flag, 0);
    proj_kernel<D_, 0><<<dim3(M / 64, 1), 256, 0, stream>>>(x, Wk, bk, kk, flag, 0);

    for (int b0 = 0; b0 < B_; b0 += BHg) {
        const size_t xoff = (size_t)b0 * N_ * C_;
        const size_t qoff = (size_t)b0 * N_ * D_;
        proj_kernel<C_, 1><<<dim3(BHg * N_ / 64, C_ / 64), 256, 0, stream>>>(
            x, Wv, bv, vt, flag, xoff);
        gemm128<64, 64, 64, 0><<<dim3(16, 16, BHg), 256, 0, stream>>>(
            q + qoff, kk + qoff, S, lrow, x, gamma, d_out, flag, b0,
            (size_t)N_ * D_, (size_t)N_ * D_);
        softmax_kernel<<<dim3(BHg * 512), 256, 0, stream>>>(S, lrow);
        gemm128<2048, 2048, 2048, 1><<<dim3(16, 4, BHg), 256, 0, stream>>>(
            S, vt, S, lrow, x, gamma, d_out, flag, b0,
            (size_t)N_ * N_, (size_t)C_ * N_);
    }
}